// Round 3
// baseline (150.311 us; speedup 1.0000x reference)
//
#include <hip/hip_runtime.h>

static constexpr int  D   = 64;        // embedding dim (C)
static constexpr int  KC  = 1024;      // codebook size
static constexpr int  HW  = 4096;      // 64*64
static constexpr long QSZ = 16L*64*64*64;  // elems per output tensor
static constexpr float DELTA = 0.02f;  // bf16-split score error ~2e-3; 10x margin

// ---- d_ws layout (bytes) ----
static constexpr size_t WS_ENORM = 0;        // f32[1024]
static constexpr size_t WS_EHI   = 4096;     // u16[65536] bf16 hi
static constexpr size_t WS_ELO   = 135168;   // u16[65536] bf16 lo
static constexpr size_t WS_CNT   = 266240;   // i32 flagged-row count
static constexpr size_t WS_LIST  = 266244;   // i32[65536] flagged rows
static constexpr size_t WS_NEED  = 528388;

typedef __attribute__((ext_vector_type(8))) short s16x8;   // 8 bf16 (4 VGPR)
typedef __attribute__((ext_vector_type(4))) float f32x4;   // MFMA C/D

__device__ __forceinline__ unsigned short f2bf(float x) {  // RN-even
  union { float f; unsigned u; } v; v.f = x;
  unsigned r = v.u + 0x7FFFu + ((v.u >> 16) & 1u);
  return (unsigned short)(r >> 16);
}
__device__ __forceinline__ float bf2f(unsigned short h) {
  union { unsigned u; float f; } v; v.u = ((unsigned)h) << 16; return v.f;
}

// ---------------------------------------------------------------------------
// prep: enorm[k], bf16 hi/lo split of E, zero flag counter
// ---------------------------------------------------------------------------
__global__ void __launch_bounds__(64) prep_kernel(const float* __restrict__ E,
                                                  float* __restrict__ enorm,
                                                  unsigned short* __restrict__ Ehi,
                                                  unsigned short* __restrict__ Elo,
                                                  int* __restrict__ cnt) {
  const int k = blockIdx.x, c = threadIdx.x;
  if (k == 0 && c == 0) *cnt = 0;
  const float v = E[k * D + c];
  const unsigned short hb = f2bf(v);
  Ehi[k * D + c] = hb;
  Elo[k * D + c] = f2bf(v - bf2f(hb));
  float s = v * v;
#pragma unroll
  for (int off = 32; off; off >>= 1) s += __shfl_down(s, off, 64);
  if (c == 0) enorm[k] = s;
}

// ---------------------------------------------------------------------------
// main kernel: 1024 blocks x 256 thr. Block = one (b,h) tile of 64 rows.
// The 4 waves each sweep a DISJOINT 256-col quarter of the codebook (so the
// B-load : MFMA amortization of mi=4 is kept), then merge top-2 in LDS in
// ascending column order. Small LDS (36.6 KB) + grid 1024 -> 3 blocks/CU.
// ---------------------------------------------------------------------------
__global__ void __launch_bounds__(256, 3)
vq_mfma_kernel(const float* __restrict__ X,
               const float* __restrict__ E,
               const float* __restrict__ enorm,
               const unsigned short* __restrict__ Ehi,
               const unsigned short* __restrict__ Elo,
               float* __restrict__ out,
               int* __restrict__ cnt,
               int* __restrict__ list) {
  __shared__ float Xt[64][65];    // Xt[w][c] = X[b][c][h][w]
  __shared__ float eq[64][65];
  __shared__ float sc1[4][64];
  __shared__ float sc2[4][64];
  __shared__ int   ids[4][64];
  __shared__ int   idx_s[64];

  const int tid  = threadIdx.x;
  const int wave = tid >> 6;
  const int lane = tid & 63;
  const int bh   = blockIdx.x;
  const int b    = bh >> 6;
  const int h    = bh & 63;

  // ---- phase A: stage 64x64 X-slice transposed to row-major ----
  const float* __restrict__ xbase = X + (size_t)b * (D * HW) + h * 64;
  {
    const int w = tid & 63, c0 = tid >> 6;
#pragma unroll
    for (int i = 0; i < 16; ++i)
      Xt[w][c0 + i * 4] = xbase[(c0 + i * 4) * HW + w];  // coalesced; 2-way LDS (free)
  }
  __syncthreads();

  // ---- phase B: A-fragments (bf16 hi/lo) for the 64 rows (same per wave) ----
  s16x8 ah[4][2], al[4][2];
#pragma unroll
  for (int mi = 0; mi < 4; ++mi) {
    const int row = mi * 16 + (lane & 15);
#pragma unroll
    for (int ks = 0; ks < 2; ++ks) {
      const float* xp = &Xt[row][ks * 32 + (lane >> 4) * 8];
      s16x8 hh, ll;
#pragma unroll
      for (int j = 0; j < 8; ++j) {
        const float x = xp[j];
        const unsigned short hb = f2bf(x);
        hh[j] = (short)hb;
        ll[j] = (short)f2bf(x - bf2f(hb));
      }
      ah[mi][ks] = hh; al[mi][ks] = ll;
    }
  }

  // ---- phase C: sweep this wave's 256-col quarter (4 chunks of 64) ----
  float b1[4][4], b2[4][4]; int i1[4][4];
#pragma unroll
  for (int mi = 0; mi < 4; ++mi)
#pragma unroll
    for (int r = 0; r < 4; ++r) { b1[mi][r] = 3.4e38f; b2[mi][r] = 3.4e38f; i1[mi][r] = 0; }

  const int cbase = wave * 256;
  for (int chunk = 0; chunk < 4; ++chunk) {
#pragma unroll
    for (int ni = 0; ni < 4; ++ni) {
      const int col = cbase + chunk * 64 + ni * 16 + (lane & 15);
      const int k0a = (lane >> 4) * 8;
      const s16x8 bh0 = *(const s16x8*)(Ehi + (size_t)col * D + k0a);
      const s16x8 bh1 = *(const s16x8*)(Ehi + (size_t)col * D + 32 + k0a);
      const s16x8 bl0 = *(const s16x8*)(Elo + (size_t)col * D + k0a);
      const s16x8 bl1 = *(const s16x8*)(Elo + (size_t)col * D + 32 + k0a);
      const float en = enorm[col];
#pragma unroll
      for (int mi = 0; mi < 4; ++mi) {
        f32x4 acc = {0.f, 0.f, 0.f, 0.f};
        acc = __builtin_amdgcn_mfma_f32_16x16x32_bf16(ah[mi][0], bh0, acc, 0, 0, 0);
        acc = __builtin_amdgcn_mfma_f32_16x16x32_bf16(ah[mi][0], bl0, acc, 0, 0, 0);
        acc = __builtin_amdgcn_mfma_f32_16x16x32_bf16(al[mi][0], bh0, acc, 0, 0, 0);
        acc = __builtin_amdgcn_mfma_f32_16x16x32_bf16(ah[mi][1], bh1, acc, 0, 0, 0);
        acc = __builtin_amdgcn_mfma_f32_16x16x32_bf16(ah[mi][1], bl1, acc, 0, 0, 0);
        acc = __builtin_amdgcn_mfma_f32_16x16x32_bf16(al[mi][1], bh1, acc, 0, 0, 0);
#pragma unroll
        for (int r = 0; r < 4; ++r) {
          const float s   = fmaf(-2.f, acc[r], en);
          const float nb2 = __builtin_amdgcn_fmed3f(b1[mi][r], s, b2[mi][r]);
          const bool  lt  = s < b1[mi][r];
          b1[mi][r] = fminf(b1[mi][r], s);
          i1[mi][r] = lt ? col : i1[mi][r];
          b2[mi][r] = nb2;
        }
      }
    }
  }

  // ---- phase D1: merge top-2 across the 16 col-lanes of this wave ----
#pragma unroll
  for (int mi = 0; mi < 4; ++mi) {
#pragma unroll
    for (int r = 0; r < 4; ++r) {
      float B1 = b1[mi][r], B2 = b2[mi][r]; int I1 = i1[mi][r];
#pragma unroll
      for (int m = 1; m < 16; m <<= 1) {
        const float o1 = __shfl_xor(B1, m, 64);
        const float o2 = __shfl_xor(B2, m, 64);
        const int   oi = __shfl_xor(I1, m, 64);
        const float n2 = fminf(fminf(B2, o2), fmaxf(B1, o1));
        if (o1 < B1) { B1 = o1; I1 = oi; }
        B2 = n2;
      }
      if ((lane & 15) == 0) {
        const int rl = mi * 16 + (lane >> 4) * 4 + r;
        sc1[wave][rl] = B1; sc2[wave][rl] = B2; ids[wave][rl] = I1;
      }
    }
  }
  __syncthreads();

  // ---- phase D2: merge the 4 wave quarters (ascending col order) ----
  if (tid < 64) {
    float g1 = sc1[0][tid], g2 = sc2[0][tid]; int gi = ids[0][tid];
#pragma unroll
    for (int wv = 1; wv < 4; ++wv) {
      const float s1 = sc1[wv][tid], s2 = sc2[wv][tid];
      const int   ii = ids[wv][tid];
      if (s1 < g1) { g2 = fminf(g1, s2); g1 = s1; gi = ii; }
      else         { g2 = fminf(g2, s1); }
    }
    idx_s[tid] = gi;
    if (g2 - g1 < DELTA) {                  // near-tie -> exact recheck
      const int pos = atomicAdd(cnt, 1);
      list[pos] = bh * 64 + tid;
    }
  }
  __syncthreads();

  // ---- phase E: outputs (coalesced via LDS transpose tiles) ----
  float* __restrict__ qout = out;
  float* __restrict__ lat  = out + QSZ;
  float* __restrict__ ql   = out + 2 * QSZ;
  const size_t n0 = (size_t)bh * 64;

#pragma unroll
  for (int i = 0; i < 16; ++i) {
    const int e_ = i * 256 + tid;
    const int w = e_ >> 6, c = e_ & 63;
    const float q = E[idx_s[w] * D + c];    // coalesced gather (w uniform/group)
    eq[w][c] = q;
    ql[(n0 + w) * D + c]  = q;
    lat[(n0 + w) * D + c] = Xt[w][c];
  }
  __syncthreads();
  float* __restrict__ qb = qout + (size_t)b * (D * HW) + h * 64;
#pragma unroll
  for (int i = 0; i < 16; ++i) {
    const int e_ = i * 256 + tid;
    const int c = e_ >> 6, w = e_ & 63;
    qb[c * HW + w] = eq[w][c];
  }
}

// ---------------------------------------------------------------------------
// exact fp32 recheck for flagged rows (lowest-index tie-break), 1 wave/row
// ---------------------------------------------------------------------------
__global__ void __launch_bounds__(64) recheck_kernel(const float* __restrict__ X,
                                                     const float* __restrict__ E,
                                                     const float* __restrict__ enorm,
                                                     const int* __restrict__ cnt,
                                                     const int* __restrict__ list,
                                                     float* __restrict__ out) {
  __shared__ float fsh[64];
  const int lane = threadIdx.x;
  const int n = *cnt;
  for (int ii = blockIdx.x; ii < n; ii += gridDim.x) {
    const int row = list[ii];
    const int b = row >> 12, h = (row >> 6) & 63, w = row & 63;
    fsh[lane] = X[((size_t)b * D + lane) * HW + h * 64 + w];
    __syncthreads();
    float best = 3.4e38f; int bidx = 0;
    for (int j = 0; j < 16; ++j) {
      const int k = lane + j * 64;
      const float* __restrict__ e = E + k * D;
      float a0 = 0.f, a1 = 0.f, a2 = 0.f, a3 = 0.f;
#pragma unroll
      for (int c = 0; c < D; c += 4) {
        a0 = fmaf(fsh[c + 0], e[c + 0], a0);
        a1 = fmaf(fsh[c + 1], e[c + 1], a1);
        a2 = fmaf(fsh[c + 2], e[c + 2], a2);
        a3 = fmaf(fsh[c + 3], e[c + 3], a3);
      }
      const float s = enorm[k] - 2.0f * ((a0 + a1) + (a2 + a3));
      if (s < best) { best = s; bidx = k; }
    }
#pragma unroll
    for (int m = 1; m < 64; m <<= 1) {
      const float ob = __shfl_xor(best, m, 64);
      const int   oi = __shfl_xor(bidx, m, 64);
      if (ob < best || (ob == best && oi < bidx)) { best = ob; bidx = oi; }
    }
    const float q = E[bidx * D + lane];
    float* __restrict__ ql = out + 2 * QSZ;
    ql[(size_t)row * D + lane] = q;
    out[((size_t)b * D + lane) * HW + h * 64 + w] = q;
    __syncthreads();
  }
}

// ---------------------------------------------------------------------------
// fallback (R1 kernels) if ws_size is too small for the bf16 tables
// ---------------------------------------------------------------------------
__global__ void __launch_bounds__(64) enorm_kernel(const float* __restrict__ E,
                                                   float* __restrict__ enorm) {
  const int k = blockIdx.x, c = threadIdx.x;
  float v = E[k * D + c];
  float s = v * v;
#pragma unroll
  for (int off = 32; off; off >>= 1) s += __shfl_down(s, off, 64);
  if (c == 0) enorm[k] = s;
}

__global__ void __launch_bounds__(256) vq_kernel(const float* __restrict__ X,
                                                 const float* __restrict__ E,
                                                 const float* __restrict__ enorm,
                                                 float* __restrict__ out) {
  const int bh = blockIdx.x, b = bh >> 6, h = bh & 63;
  const int tid = threadIdx.x, wave = tid >> 6, lane = tid & 63;
  const float* __restrict__ xbase = X + (size_t)b * (D * HW) + h * 64;
  float f[D];
#pragma unroll
  for (int c = 0; c < D; ++c) f[c] = xbase[c * HW + lane];
  float best = 3.4e38f; int bidx = 0;
  const int k0 = wave * (KC / 4);
  for (int k = k0; k < k0 + (KC / 4); ++k) {
    const float* __restrict__ e = E + k * D;
    float a0 = 0.f, a1 = 0.f, a2 = 0.f, a3 = 0.f;
#pragma unroll
    for (int c = 0; c < D; c += 4) {
      a0 = fmaf(f[c + 0], e[c + 0], a0);
      a1 = fmaf(f[c + 1], e[c + 1], a1);
      a2 = fmaf(f[c + 2], e[c + 2], a2);
      a3 = fmaf(f[c + 3], e[c + 3], a3);
    }
    const float score = enorm[k] - 2.0f * ((a0 + a1) + (a2 + a3));
    if (score < best) { best = score; bidx = k; }
  }
  __shared__ float sc_s[4][64]; __shared__ int id_s[4][64];
  __shared__ int idx_s[64]; __shared__ float tile[64 * 65]; __shared__ float eq[64 * 65];
  sc_s[wave][lane] = best; id_s[wave][lane] = bidx;
  if (wave == 0) {
#pragma unroll
    for (int c = 0; c < D; ++c) tile[c * 65 + lane] = f[c];
  }
  __syncthreads();
  if (tid < 64) {
    float bs = sc_s[0][tid]; int bi = id_s[0][tid];
#pragma unroll
    for (int wv = 1; wv < 4; ++wv) {
      if (sc_s[wv][tid] < bs) { bs = sc_s[wv][tid]; bi = id_s[wv][tid]; }
    }
    idx_s[tid] = bi;
  }
  __syncthreads();
  float* __restrict__ qout = out;
  float* __restrict__ lat = out + QSZ;
  float* __restrict__ ql = out + 2 * QSZ;
  const size_t n0 = (size_t)bh * 64;
#pragma unroll
  for (int i = 0; i < 16; ++i) {
    const int e_ = i * 256 + tid, w = e_ >> 6, c = e_ & 63;
    const float q = E[idx_s[w] * D + c];
    eq[w * 65 + c] = q;
    ql[(n0 + w) * D + c] = q;
    lat[(n0 + w) * D + c] = tile[c * 65 + w];
  }
  __syncthreads();
  float* __restrict__ qb = qout + (size_t)b * (D * HW) + h * 64;
#pragma unroll
  for (int i = 0; i < 16; ++i) {
    const int e_ = i * 256 + tid, c = e_ >> 6, w = e_ & 63;
    qb[c * HW + w] = eq[w * 65 + c];
  }
}

extern "C" void kernel_launch(void* const* d_in, const int* in_sizes, int n_in,
                              void* d_out, int out_size, void* d_ws, size_t ws_size,
                              hipStream_t stream) {
  const float* X = (const float*)d_in[0];
  const float* E = (const float*)d_in[1];
  float* out = (float*)d_out;
  char* ws = (char*)d_ws;

  if (ws_size >= WS_NEED) {
    float* enorm = (float*)(ws + WS_ENORM);
    unsigned short* Ehi = (unsigned short*)(ws + WS_EHI);
    unsigned short* Elo = (unsigned short*)(ws + WS_ELO);
    int* cnt  = (int*)(ws + WS_CNT);
    int* list = (int*)(ws + WS_LIST);
    prep_kernel<<<KC, 64, 0, stream>>>(E, enorm, Ehi, Elo, cnt);
    vq_mfma_kernel<<<1024, 256, 0, stream>>>(X, E, enorm, Ehi, Elo, out, cnt, list);
    recheck_kernel<<<512, 64, 0, stream>>>(X, E, enorm, cnt, list, out);
  } else {
    float* enorm = (float*)ws;
    enorm_kernel<<<KC, 64, 0, stream>>>(E, enorm);
    vq_kernel<<<1024, 256, 0, stream>>>(X, E, enorm, out);
  }
}

// Round 4
// 106.018 us; speedup vs baseline: 1.4178x; 1.4178x over previous
//
#include <hip/hip_runtime.h>

static constexpr int  D   = 64;        // embedding dim (C)
static constexpr int  KC  = 1024;      // codebook size
static constexpr int  HW  = 4096;      // 64*64
static constexpr long QSZ = 16L*64*64*64;  // elems per output tensor
static constexpr float DELTA = 0.02f;  // bf16-split score error ~2e-3; 10x margin

// ---- d_ws layout (bytes) ----
static constexpr size_t WS_ENORM = 0;        // f32[1024]
static constexpr size_t WS_EHI   = 4096;     // u16[65536] bf16 hi
static constexpr size_t WS_ELO   = 135168;   // u16[65536] bf16 lo
static constexpr size_t WS_CNT   = 266240;   // i32 flagged-row count
static constexpr size_t WS_LIST  = 266244;   // i32[65536] flagged rows
static constexpr size_t WS_NEED  = 528388;

typedef __attribute__((ext_vector_type(8))) short s16x8;   // 8 bf16 (4 VGPR)
typedef __attribute__((ext_vector_type(4))) float f32x4;   // MFMA C/D

__device__ __forceinline__ unsigned short f2bf(float x) {  // RN-even
  union { float f; unsigned u; } v; v.f = x;
  unsigned r = v.u + 0x7FFFu + ((v.u >> 16) & 1u);
  return (unsigned short)(r >> 16);
}
__device__ __forceinline__ float bf2f(unsigned short h) {
  union { unsigned u; float f; } v; v.u = ((unsigned)h) << 16; return v.f;
}

// ---------------------------------------------------------------------------
// prep: enorm[k], bf16 hi/lo split of E, zero flag counter
// ---------------------------------------------------------------------------
__global__ void __launch_bounds__(64) prep_kernel(const float* __restrict__ E,
                                                  float* __restrict__ enorm,
                                                  unsigned short* __restrict__ Ehi,
                                                  unsigned short* __restrict__ Elo,
                                                  int* __restrict__ cnt) {
  const int k = blockIdx.x, c = threadIdx.x;
  if (k == 0 && c == 0) *cnt = 0;
  const float v = E[k * D + c];
  const unsigned short hb = f2bf(v);
  Ehi[k * D + c] = hb;
  Elo[k * D + c] = f2bf(v - bf2f(hb));
  float s = v * v;
#pragma unroll
  for (int off = 32; off; off >>= 1) s += __shfl_down(s, off, 64);
  if (c == 0) enorm[k] = s;
}

// ---------------------------------------------------------------------------
// main kernel: 1024 blocks x 256 thr. Block = one (b,h) tile of 64 rows.
// Wave w = (rowhalf rh = w>>1, K-half kh = w&1): 32 rows (mi=2) x 512 cols.
// Register budget: ah/al 32 + top2 24 + transients ~50 => ~110 VGPR, no
// spill under launch_bounds(256,2). LDS ~18 KB (eq tile merged into Xt).
// ---------------------------------------------------------------------------
__global__ void __launch_bounds__(256, 2)
vq_mfma_kernel(const float* __restrict__ X,
               const float* __restrict__ E,
               const float* __restrict__ enorm,
               const unsigned short* __restrict__ Ehi,
               const unsigned short* __restrict__ Elo,
               float* __restrict__ out,
               int* __restrict__ cnt,
               int* __restrict__ list) {
  __shared__ float Xt[64][65];    // Xt[w][c] = X[b][c][h][w]; reused for E-gather
  __shared__ float sc1[2][64];
  __shared__ float sc2[2][64];
  __shared__ int   ids[2][64];
  __shared__ int   idx_s[64];

  const int tid  = threadIdx.x;
  const int wave = tid >> 6;
  const int lane = tid & 63;
  const int rh   = wave >> 1;      // row half: rows rh*32 .. rh*32+31
  const int kh   = wave & 1;       // K half:  cols kh*512 .. kh*512+511
  const int bh   = blockIdx.x;
  const int b    = bh >> 6;
  const int h    = bh & 63;

  // ---- phase A: stage 64x64 X-slice transposed to row-major ----
  const float* __restrict__ xbase = X + (size_t)b * (D * HW) + h * 64;
  {
    const int w = tid & 63, c0 = tid >> 6;
#pragma unroll
    for (int i = 0; i < 16; ++i)
      Xt[w][c0 + i * 4] = xbase[(c0 + i * 4) * HW + w];  // coalesced; 2-way LDS (free)
  }
  __syncthreads();

  // ---- phase B: A-fragments (bf16 hi/lo) for this wave's 32 rows ----
  s16x8 ah[2][2], al[2][2];
#pragma unroll
  for (int mi = 0; mi < 2; ++mi) {
    const int row = rh * 32 + mi * 16 + (lane & 15);
#pragma unroll
    for (int ks = 0; ks < 2; ++ks) {
      const float* xp = &Xt[row][ks * 32 + (lane >> 4) * 8];
      s16x8 hh, ll;
#pragma unroll
      for (int j = 0; j < 8; ++j) {
        const float x = xp[j];
        const unsigned short hb = f2bf(x);
        hh[j] = (short)hb;
        ll[j] = (short)f2bf(x - bf2f(hb));
      }
      ah[mi][ks] = hh; al[mi][ks] = ll;
    }
  }

  // ---- phase C: sweep this wave's 512-col half (8 chunks of 64) ----
  float b1[2][4], b2[2][4]; int i1[2][4];
#pragma unroll
  for (int mi = 0; mi < 2; ++mi)
#pragma unroll
    for (int r = 0; r < 4; ++r) { b1[mi][r] = 3.4e38f; b2[mi][r] = 3.4e38f; i1[mi][r] = 0; }

  const int cbase = kh * 512;
  for (int chunk = 0; chunk < 8; ++chunk) {
#pragma unroll
    for (int ni = 0; ni < 4; ++ni) {
      const int col = cbase + chunk * 64 + ni * 16 + (lane & 15);
      const int k0a = (lane >> 4) * 8;
      const s16x8 bh0 = *(const s16x8*)(Ehi + (size_t)col * D + k0a);
      const s16x8 bh1 = *(const s16x8*)(Ehi + (size_t)col * D + 32 + k0a);
      const s16x8 bl0 = *(const s16x8*)(Elo + (size_t)col * D + k0a);
      const s16x8 bl1 = *(const s16x8*)(Elo + (size_t)col * D + 32 + k0a);
      const float en = enorm[col];
#pragma unroll
      for (int mi = 0; mi < 2; ++mi) {
        f32x4 acc = {0.f, 0.f, 0.f, 0.f};
        acc = __builtin_amdgcn_mfma_f32_16x16x32_bf16(ah[mi][0], bh0, acc, 0, 0, 0);
        acc = __builtin_amdgcn_mfma_f32_16x16x32_bf16(ah[mi][0], bl0, acc, 0, 0, 0);
        acc = __builtin_amdgcn_mfma_f32_16x16x32_bf16(al[mi][0], bh0, acc, 0, 0, 0);
        acc = __builtin_amdgcn_mfma_f32_16x16x32_bf16(ah[mi][1], bh1, acc, 0, 0, 0);
        acc = __builtin_amdgcn_mfma_f32_16x16x32_bf16(ah[mi][1], bl1, acc, 0, 0, 0);
        acc = __builtin_amdgcn_mfma_f32_16x16x32_bf16(al[mi][1], bh1, acc, 0, 0, 0);
#pragma unroll
        for (int r = 0; r < 4; ++r) {
          const float s   = fmaf(-2.f, acc[r], en);
          const float nb2 = __builtin_amdgcn_fmed3f(b1[mi][r], s, b2[mi][r]);
          const bool  lt  = s < b1[mi][r];
          b1[mi][r] = fminf(b1[mi][r], s);
          i1[mi][r] = lt ? col : i1[mi][r];
          b2[mi][r] = nb2;
        }
      }
    }
  }

  // ---- phase D1: merge top-2 across the 16 col-lanes of this wave ----
#pragma unroll
  for (int mi = 0; mi < 2; ++mi) {
#pragma unroll
    for (int r = 0; r < 4; ++r) {
      float B1 = b1[mi][r], B2 = b2[mi][r]; int I1 = i1[mi][r];
#pragma unroll
      for (int m = 1; m < 16; m <<= 1) {
        const float o1 = __shfl_xor(B1, m, 64);
        const float o2 = __shfl_xor(B2, m, 64);
        const int   oi = __shfl_xor(I1, m, 64);
        const float n2 = fminf(fminf(B2, o2), fmaxf(B1, o1));
        if (o1 < B1) { B1 = o1; I1 = oi; }
        B2 = n2;
      }
      if ((lane & 15) == 0) {
        const int rl = rh * 32 + mi * 16 + (lane >> 4) * 4 + r;  // global row in tile
        sc1[kh][rl] = B1; sc2[kh][rl] = B2; ids[kh][rl] = I1;
      }
    }
  }
  __syncthreads();

  // ---- phase D2: merge the 2 K-halves (ascending col order) ----
  if (tid < 64) {
    float g1 = sc1[0][tid], g2 = sc2[0][tid]; int gi = ids[0][tid];
    {
      const float s1 = sc1[1][tid], s2 = sc2[1][tid];
      const int   ii = ids[1][tid];
      if (s1 < g1) { g2 = fminf(g1, s2); g1 = s1; gi = ii; }
      else         { g2 = fminf(g2, s1); }
    }
    idx_s[tid] = gi;
    if (g2 - g1 < DELTA) {                  // near-tie -> exact recheck
      const int pos = atomicAdd(cnt, 1);
      list[pos] = bh * 64 + tid;
    }
  }
  __syncthreads();

  // ---- phase E: outputs (coalesced; eq tile overlaid onto Xt) ----
  float* __restrict__ qout = out;
  float* __restrict__ lat  = out + QSZ;
  float* __restrict__ ql   = out + 2 * QSZ;
  const size_t n0 = (size_t)bh * 64;

#pragma unroll
  for (int i = 0; i < 16; ++i) {
    const int e_ = i * 256 + tid;
    const int w = e_ >> 6, c = e_ & 63;
    const float q = E[idx_s[w] * D + c];    // coalesced gather (w uniform/group)
    ql[(n0 + w) * D + c]  = q;
    lat[(n0 + w) * D + c] = Xt[w][c];
    Xt[w][c] = q;                            // overlay: each (w,c) read then written once
  }
  __syncthreads();
  float* __restrict__ qb = qout + (size_t)b * (D * HW) + h * 64;
#pragma unroll
  for (int i = 0; i < 16; ++i) {
    const int e_ = i * 256 + tid;
    const int c = e_ >> 6, w = e_ & 63;
    qb[c * HW + w] = Xt[w][c];
  }
}

// ---------------------------------------------------------------------------
// exact fp32 recheck for flagged rows (lowest-index tie-break), 1 wave/row
// ---------------------------------------------------------------------------
__global__ void __launch_bounds__(64) recheck_kernel(const float* __restrict__ X,
                                                     const float* __restrict__ E,
                                                     const float* __restrict__ enorm,
                                                     const int* __restrict__ cnt,
                                                     const int* __restrict__ list,
                                                     float* __restrict__ out) {
  __shared__ float fsh[64];
  const int lane = threadIdx.x;
  const int n = *cnt;
  for (int ii = blockIdx.x; ii < n; ii += gridDim.x) {
    const int row = list[ii];
    const int b = row >> 12, h = (row >> 6) & 63, w = row & 63;
    fsh[lane] = X[((size_t)b * D + lane) * HW + h * 64 + w];
    __syncthreads();
    float best = 3.4e38f; int bidx = 0;
    for (int j = 0; j < 16; ++j) {
      const int k = lane + j * 64;
      const float* __restrict__ e = E + k * D;
      float a0 = 0.f, a1 = 0.f, a2 = 0.f, a3 = 0.f;
#pragma unroll
      for (int c = 0; c < D; c += 4) {
        a0 = fmaf(fsh[c + 0], e[c + 0], a0);
        a1 = fmaf(fsh[c + 1], e[c + 1], a1);
        a2 = fmaf(fsh[c + 2], e[c + 2], a2);
        a3 = fmaf(fsh[c + 3], e[c + 3], a3);
      }
      const float s = enorm[k] - 2.0f * ((a0 + a1) + (a2 + a3));
      if (s < best) { best = s; bidx = k; }
    }
#pragma unroll
    for (int m = 1; m < 64; m <<= 1) {
      const float ob = __shfl_xor(best, m, 64);
      const int   oi = __shfl_xor(bidx, m, 64);
      if (ob < best || (ob == best && oi < bidx)) { best = ob; bidx = oi; }
    }
    const float q = E[bidx * D + lane];
    float* __restrict__ ql = out + 2 * QSZ;
    ql[(size_t)row * D + lane] = q;
    out[((size_t)b * D + lane) * HW + h * 64 + w] = q;
    __syncthreads();
  }
}

// ---------------------------------------------------------------------------
// fallback (R1 kernels) if ws_size is too small for the bf16 tables
// ---------------------------------------------------------------------------
__global__ void __launch_bounds__(64) enorm_kernel(const float* __restrict__ E,
                                                   float* __restrict__ enorm) {
  const int k = blockIdx.x, c = threadIdx.x;
  float v = E[k * D + c];
  float s = v * v;
#pragma unroll
  for (int off = 32; off; off >>= 1) s += __shfl_down(s, off, 64);
  if (c == 0) enorm[k] = s;
}

__global__ void __launch_bounds__(256) vq_kernel(const float* __restrict__ X,
                                                 const float* __restrict__ E,
                                                 const float* __restrict__ enorm,
                                                 float* __restrict__ out) {
  const int bh = blockIdx.x, b = bh >> 6, h = bh & 63;
  const int tid = threadIdx.x, wave = tid >> 6, lane = tid & 63;
  const float* __restrict__ xbase = X + (size_t)b * (D * HW) + h * 64;
  float f[D];
#pragma unroll
  for (int c = 0; c < D; ++c) f[c] = xbase[c * HW + lane];
  float best = 3.4e38f; int bidx = 0;
  const int k0 = wave * (KC / 4);
  for (int k = k0; k < k0 + (KC / 4); ++k) {
    const float* __restrict__ e = E + k * D;
    float a0 = 0.f, a1 = 0.f, a2 = 0.f, a3 = 0.f;
#pragma unroll
    for (int c = 0; c < D; c += 4) {
      a0 = fmaf(f[c + 0], e[c + 0], a0);
      a1 = fmaf(f[c + 1], e[c + 1], a1);
      a2 = fmaf(f[c + 2], e[c + 2], a2);
      a3 = fmaf(f[c + 3], e[c + 3], a3);
    }
    const float score = enorm[k] - 2.0f * ((a0 + a1) + (a2 + a3));
    if (score < best) { best = score; bidx = k; }
  }
  __shared__ float sc_s[4][64]; __shared__ int id_s[4][64];
  __shared__ int idx_s[64]; __shared__ float tile[64 * 65]; __shared__ float eq[64 * 65];
  sc_s[wave][lane] = best; id_s[wave][lane] = bidx;
  if (wave == 0) {
#pragma unroll
    for (int c = 0; c < D; ++c) tile[c * 65 + lane] = f[c];
  }
  __syncthreads();
  if (tid < 64) {
    float bs = sc_s[0][tid]; int bi = id_s[0][tid];
#pragma unroll
    for (int wv = 1; wv < 4; ++wv) {
      if (sc_s[wv][tid] < bs) { bs = sc_s[wv][tid]; bi = id_s[wv][tid]; }
    }
    idx_s[tid] = bi;
  }
  __syncthreads();
  float* __restrict__ qout = out;
  float* __restrict__ lat = out + QSZ;
  float* __restrict__ ql = out + 2 * QSZ;
  const size_t n0 = (size_t)bh * 64;
#pragma unroll
  for (int i = 0; i < 16; ++i) {
    const int e_ = i * 256 + tid, w = e_ >> 6, c = e_ & 63;
    const float q = E[idx_s[w] * D + c];
    eq[w * 65 + c] = q;
    ql[(n0 + w) * D + c] = q;
    lat[(n0 + w) * D + c] = tile[c * 65 + w];
  }
  __syncthreads();
  float* __restrict__ qb = qout + (size_t)b * (D * HW) + h * 64;
#pragma unroll
  for (int i = 0; i < 16; ++i) {
    const int e_ = i * 256 + tid, c = e_ >> 6, w = e_ & 63;
    qb[c * HW + w] = eq[w * 65 + c];
  }
}

extern "C" void kernel_launch(void* const* d_in, const int* in_sizes, int n_in,
                              void* d_out, int out_size, void* d_ws, size_t ws_size,
                              hipStream_t stream) {
  const float* X = (const float*)d_in[0];
  const float* E = (const float*)d_in[1];
  float* out = (float*)d_out;
  char* ws = (char*)d_ws;

  if (ws_size >= WS_NEED) {
    float* enorm = (float*)(ws + WS_ENORM);
    unsigned short* Ehi = (unsigned short*)(ws + WS_EHI);
    unsigned short* Elo = (unsigned short*)(ws + WS_ELO);
    int* cnt  = (int*)(ws + WS_CNT);
    int* list = (int*)(ws + WS_LIST);
    prep_kernel<<<KC, 64, 0, stream>>>(E, enorm, Ehi, Elo, cnt);
    vq_mfma_kernel<<<1024, 256, 0, stream>>>(X, E, enorm, Ehi, Elo, out, cnt, list);
    recheck_kernel<<<512, 64, 0, stream>>>(X, E, enorm, cnt, list, out);
  } else {
    float* enorm = (float*)ws;
    enorm_kernel<<<KC, 64, 0, stream>>>(E, enorm);
    vq_kernel<<<1024, 256, 0, stream>>>(X, E, enorm, out);
  }
}

// Round 6
// 101.174 us; speedup vs baseline: 1.4857x; 1.0479x over previous
//
#include <hip/hip_runtime.h>

static constexpr int  D   = 64;        // embedding dim (C)
static constexpr int  KC  = 1024;      // codebook size
static constexpr int  HW  = 4096;      // 64*64
static constexpr long QSZ = 16L*64*64*64;  // elems per output tensor
static constexpr float GAPT = 0.01f;   // acc-domain gap (= d-gap 0.02); split err ~1e-3

// ---- d_ws layout (bytes) ----
static constexpr size_t WS_ENORM = 0;        // f32[1024]  sum e^2 (recheck)
static constexpr size_t WS_ENH   = 4096;     // f32[1024]  -0.5*sum e^2 (C-init)
static constexpr size_t WS_EHI   = 8192;     // u16[65536] bf16 hi
static constexpr size_t WS_ELO   = 139264;   // u16[65536] bf16 lo
static constexpr size_t WS_CNT   = 270336;   // i32 flagged-row count
static constexpr size_t WS_LIST  = 270340;   // i32[65536] flagged rows
static constexpr size_t WS_NEED  = 532484;

typedef __attribute__((ext_vector_type(8))) short s16x8;   // 8 bf16 (4 VGPR)
typedef __attribute__((ext_vector_type(4))) float f32x4;   // MFMA C/D

__device__ __forceinline__ unsigned short f2bf(float x) {  // RN-even
  union { float f; unsigned u; } v; v.f = x;
  unsigned r = v.u + 0x7FFFu + ((v.u >> 16) & 1u);
  return (unsigned short)(r >> 16);
}
__device__ __forceinline__ float bf2f(unsigned short h) {
  union { unsigned u; float f; } v; v.u = ((unsigned)h) << 16; return v.f;
}

// ---------------------------------------------------------------------------
// prep: enorm/enormh[k], bf16 hi/lo split of E, zero flag counter
// ---------------------------------------------------------------------------
__global__ void __launch_bounds__(64) prep_kernel(const float* __restrict__ E,
                                                  float* __restrict__ enorm,
                                                  float* __restrict__ enormh,
                                                  unsigned short* __restrict__ Ehi,
                                                  unsigned short* __restrict__ Elo,
                                                  int* __restrict__ cnt) {
  const int k = blockIdx.x, c = threadIdx.x;
  if (k == 0 && c == 0) *cnt = 0;
  const float v = E[k * D + c];
  const unsigned short hb = f2bf(v);
  Ehi[k * D + c] = hb;
  Elo[k * D + c] = f2bf(v - bf2f(hb));
  float s = v * v;
#pragma unroll
  for (int off = 32; off; off >>= 1) s += __shfl_down(s, off, 64);
  if (c == 0) { enorm[k] = s; enormh[k] = -0.5f * s; }
}

// ---------------------------------------------------------------------------
// main kernel: 1024 blocks x 256 thr. Block = one (b,h) tile of 64 rows.
// Wave = (rowhalf rh, K-half kh): 32 rows (mi=2) x 512 cols, 32 flat iters.
// - C-operand init = -0.5*enorm[col] -> score IS the accumulator (argMAX,
//   exact relation s_old = -2*acc); per-row ||f||^2 cancels in argmin.
// - explicit index tracking (R4-proven): cmp + med3 + 2x cndmask = 4 VALU/score
// - 2-deep register double-buffer of B-fragments hides L2 latency.
// ---------------------------------------------------------------------------
__global__ void __launch_bounds__(256, 2)
vq_mfma_kernel(const float* __restrict__ X,
               const float* __restrict__ E,
               const float* __restrict__ enormh,
               const unsigned short* __restrict__ Ehi,
               const unsigned short* __restrict__ Elo,
               float* __restrict__ out,
               int* __restrict__ cnt,
               int* __restrict__ list) {
  __shared__ float Xt[64][65];    // Xt[w][c] = X[b][c][h][w]; reused for E-gather
  __shared__ float sc1[2][64];
  __shared__ float sc2[2][64];
  __shared__ int   ids[2][64];
  __shared__ int   idx_s[64];

  const int tid  = threadIdx.x;
  const int wave = tid >> 6;
  const int lane = tid & 63;
  const int rh   = wave >> 1;      // row half: rows rh*32 .. rh*32+31
  const int kh   = wave & 1;       // K half:  cols kh*512 .. kh*512+511
  const int bh   = blockIdx.x;
  const int b    = bh >> 6;
  const int h    = bh & 63;

  // ---- phase A: stage 64x64 X-slice transposed to row-major ----
  const float* __restrict__ xbase = X + (size_t)b * (D * HW) + h * 64;
  {
    const int w = tid & 63, c0 = tid >> 6;
#pragma unroll
    for (int i = 0; i < 16; ++i)
      Xt[w][c0 + i * 4] = xbase[(c0 + i * 4) * HW + w];  // coalesced; 2-way LDS (free)
  }
  __syncthreads();

  // ---- phase B: A-fragments (bf16 hi/lo) for this wave's 32 rows ----
  s16x8 ah[2][2], al[2][2];
#pragma unroll
  for (int mi = 0; mi < 2; ++mi) {
    const int row = rh * 32 + mi * 16 + (lane & 15);
#pragma unroll
    for (int ks = 0; ks < 2; ++ks) {
      const float* xp = &Xt[row][ks * 32 + (lane >> 4) * 8];
      s16x8 hh, ll;
#pragma unroll
      for (int j = 0; j < 8; ++j) {
        const float x = xp[j];
        const unsigned short hb = f2bf(x);
        hh[j] = (short)hb;
        ll[j] = (short)f2bf(x - bf2f(hb));
      }
      ah[mi][ks] = hh; al[mi][ks] = ll;
    }
  }

  // ---- phase C: sweep this wave's 512-col half, flat 32 iters, 2-deep pipe ----
  float b1[2][4], b2[2][4]; int i1[2][4];
#pragma unroll
  for (int mi = 0; mi < 2; ++mi)
#pragma unroll
    for (int r = 0; r < 4; ++r) { b1[mi][r] = -3.4e38f; b2[mi][r] = -3.4e38f; i1[mi][r] = 0; }

  const int c15   = lane & 15;
  const int k0a   = (lane >> 4) * 8;
  const int cbase = kh * 512;

  s16x8 Abh0, Abh1, Abl0, Abl1; float Aen;
  s16x8 Bbh0, Bbh1, Bbl0, Bbl1; float Ben;

  auto loadFrag = [&](s16x8& fb0, s16x8& fb1, s16x8& fl0, s16x8& fl1,
                      float& fen, int itv) {
    const int col = cbase + (itv << 4) + c15;
    const size_t off = (size_t)col * D + k0a;
    fb0 = *(const s16x8*)(Ehi + off);
    fb1 = *(const s16x8*)(Ehi + off + 32);
    fl0 = *(const s16x8*)(Elo + off);
    fl1 = *(const s16x8*)(Elo + off + 32);
    fen = enormh[col];
  };
  auto computeFrag = [&](const s16x8& fb0, const s16x8& fb1, const s16x8& fl0,
                         const s16x8& fl1, float fen, int itv) {
    const int col = cbase + (itv << 4) + c15;
#pragma unroll
    for (int mi = 0; mi < 2; ++mi) {
      f32x4 acc = {fen, fen, fen, fen};
      acc = __builtin_amdgcn_mfma_f32_16x16x32_bf16(ah[mi][0], fb0, acc, 0, 0, 0);
      acc = __builtin_amdgcn_mfma_f32_16x16x32_bf16(al[mi][0], fb0, acc, 0, 0, 0);
      acc = __builtin_amdgcn_mfma_f32_16x16x32_bf16(ah[mi][0], fl0, acc, 0, 0, 0);
      acc = __builtin_amdgcn_mfma_f32_16x16x32_bf16(ah[mi][1], fb1, acc, 0, 0, 0);
      acc = __builtin_amdgcn_mfma_f32_16x16x32_bf16(al[mi][1], fb1, acc, 0, 0, 0);
      acc = __builtin_amdgcn_mfma_f32_16x16x32_bf16(ah[mi][1], fl1, acc, 0, 0, 0);
#pragma unroll
      for (int r = 0; r < 4; ++r) {
        const float x  = acc[r];
        const bool  gt = x > b1[mi][r];
        b2[mi][r] = __builtin_amdgcn_fmed3f(b2[mi][r], x, b1[mi][r]);  // 2nd-best
        b1[mi][r] = gt ? x   : b1[mi][r];
        i1[mi][r] = gt ? col : i1[mi][r];
      }
    }
  };

  loadFrag(Abh0, Abh1, Abl0, Abl1, Aen, 0);
  loadFrag(Bbh0, Bbh1, Bbl0, Bbl1, Ben, 1);
  for (int t = 0; t < 16; ++t) {
    const int it0 = 2 * t, it1 = 2 * t + 1;
    computeFrag(Abh0, Abh1, Abl0, Abl1, Aen, it0);
    loadFrag(Abh0, Abh1, Abl0, Abl1, Aen, (it0 + 2) & 31);
    computeFrag(Bbh0, Bbh1, Bbl0, Bbl1, Ben, it1);
    loadFrag(Bbh0, Bbh1, Bbl0, Bbl1, Ben, (it1 + 2) & 31);
  }

  // ---- phase D1: merge best/2nd across the 16 col-lanes (MAX semantics) ----
#pragma unroll
  for (int mi = 0; mi < 2; ++mi) {
#pragma unroll
    for (int r = 0; r < 4; ++r) {
      float B1 = b1[mi][r], B2 = b2[mi][r];
      int   I1 = i1[mi][r];
#pragma unroll
      for (int m = 1; m < 16; m <<= 1) {
        const float o1 = __shfl_xor(B1, m, 64);
        const float o2 = __shfl_xor(B2, m, 64);
        const int   oi = __shfl_xor(I1, m, 64);
        const float n2 = fmaxf(fmaxf(B2, o2), fminf(B1, o1));
        if (o1 > B1) { B1 = o1; I1 = oi; }
        B2 = n2;
      }
      if ((lane & 15) == 0) {
        const int rl = rh * 32 + mi * 16 + (lane >> 4) * 4 + r;
        sc1[kh][rl] = B1; sc2[kh][rl] = B2; ids[kh][rl] = I1;
      }
    }
  }
  __syncthreads();

  // ---- phase D2: merge the 2 K-halves; flag near-ties for exact recheck ----
  if (tid < 64) {
    float g1 = sc1[0][tid], g2 = sc2[0][tid]; int gi = ids[0][tid];
    {
      const float s1 = sc1[1][tid], s2 = sc2[1][tid];
      const int   ii = ids[1][tid];
      if (s1 > g1) { g2 = fmaxf(g1, s2); g1 = s1; gi = ii; }
      else         { g2 = fmaxf(g2, s1); }
    }
    idx_s[tid] = gi;
    if (g1 - g2 < GAPT) {                  // near-tie -> exact recheck
      const int pos = atomicAdd(cnt, 1);
      list[pos] = bh * 64 + tid;
    }
  }
  __syncthreads();

  // ---- phase E: outputs (coalesced; eq tile overlaid onto Xt) ----
  float* __restrict__ qout = out;
  float* __restrict__ lat  = out + QSZ;
  float* __restrict__ ql   = out + 2 * QSZ;
  const size_t n0 = (size_t)bh * 64;

#pragma unroll
  for (int i = 0; i < 16; ++i) {
    const int e_ = i * 256 + tid;
    const int w = e_ >> 6, c = e_ & 63;
    const float q = E[idx_s[w] * D + c];    // coalesced gather (w uniform/group)
    ql[(n0 + w) * D + c]  = q;
    lat[(n0 + w) * D + c] = Xt[w][c];
    Xt[w][c] = q;                            // overlay: each slot read then written
  }
  __syncthreads();
  float* __restrict__ qb = qout + (size_t)b * (D * HW) + h * 64;
#pragma unroll
  for (int i = 0; i < 16; ++i) {
    const int e_ = i * 256 + tid;
    const int c = e_ >> 6, w = e_ & 63;
    qb[c * HW + w] = Xt[w][c];
  }
}

// ---------------------------------------------------------------------------
// exact fp32 recheck for flagged rows (lowest-index tie-break), 1 wave/row
// ---------------------------------------------------------------------------
__global__ void __launch_bounds__(64) recheck_kernel(const float* __restrict__ X,
                                                     const float* __restrict__ E,
                                                     const float* __restrict__ enorm,
                                                     const int* __restrict__ cnt,
                                                     const int* __restrict__ list,
                                                     float* __restrict__ out) {
  __shared__ float fsh[64];
  const int lane = threadIdx.x;
  const int n = *cnt;
  for (int ii = blockIdx.x; ii < n; ii += gridDim.x) {
    const int row = list[ii];
    const int b = row >> 12, h = (row >> 6) & 63, w = row & 63;
    fsh[lane] = X[((size_t)b * D + lane) * HW + h * 64 + w];
    __syncthreads();
    float best = 3.4e38f; int bidx = 0;
    for (int j = 0; j < 16; ++j) {
      const int k = lane + j * 64;
      const float* __restrict__ e = E + k * D;
      float a0 = 0.f, a1 = 0.f, a2 = 0.f, a3 = 0.f;
#pragma unroll
      for (int c = 0; c < D; c += 4) {
        a0 = fmaf(fsh[c + 0], e[c + 0], a0);
        a1 = fmaf(fsh[c + 1], e[c + 1], a1);
        a2 = fmaf(fsh[c + 2], e[c + 2], a2);
        a3 = fmaf(fsh[c + 3], e[c + 3], a3);
      }
      const float s = enorm[k] - 2.0f * ((a0 + a1) + (a2 + a3));
      if (s < best) { best = s; bidx = k; }
    }
#pragma unroll
    for (int m = 1; m < 64; m <<= 1) {
      const float ob = __shfl_xor(best, m, 64);
      const int   oi = __shfl_xor(bidx, m, 64);
      if (ob < best || (ob == best && oi < bidx)) { best = ob; bidx = oi; }
    }
    const float q = E[bidx * D + lane];
    float* __restrict__ ql = out + 2 * QSZ;
    ql[(size_t)row * D + lane] = q;
    out[((size_t)b * D + lane) * HW + h * 64 + w] = q;
    __syncthreads();
  }
}

// ---------------------------------------------------------------------------
// fallback (R1 kernels) if ws_size is too small for the bf16 tables
// ---------------------------------------------------------------------------
__global__ void __launch_bounds__(64) enorm_kernel(const float* __restrict__ E,
                                                   float* __restrict__ enorm) {
  const int k = blockIdx.x, c = threadIdx.x;
  float v = E[k * D + c];
  float s = v * v;
#pragma unroll
  for (int off = 32; off; off >>= 1) s += __shfl_down(s, off, 64);
  if (c == 0) enorm[k] = s;
}

__global__ void __launch_bounds__(256) vq_kernel(const float* __restrict__ X,
                                                 const float* __restrict__ E,
                                                 const float* __restrict__ enorm,
                                                 float* __restrict__ out) {
  const int bh = blockIdx.x, b = bh >> 6, h = bh & 63;
  const int tid = threadIdx.x, wave = tid >> 6, lane = tid & 63;
  const float* __restrict__ xbase = X + (size_t)b * (D * HW) + h * 64;
  float f[D];
#pragma unroll
  for (int c = 0; c < D; ++c) f[c] = xbase[c * HW + lane];
  float best = 3.4e38f; int bidx = 0;
  const int k0 = wave * (KC / 4);
  for (int k = k0; k < k0 + (KC / 4); ++k) {
    const float* __restrict__ e = E + k * D;
    float a0 = 0.f, a1 = 0.f, a2 = 0.f, a3 = 0.f;
#pragma unroll
    for (int c = 0; c < D; c += 4) {
      a0 = fmaf(f[c + 0], e[c + 0], a0);
      a1 = fmaf(f[c + 1], e[c + 1], a1);
      a2 = fmaf(f[c + 2], e[c + 2], a2);
      a3 = fmaf(f[c + 3], e[c + 3], a3);
    }
    const float score = enorm[k] - 2.0f * ((a0 + a1) + (a2 + a3));
    if (score < best) { best = score; bidx = k; }
  }
  __shared__ float sc_s[4][64]; __shared__ int id_s[4][64];
  __shared__ int idx_s[64]; __shared__ float tile[64 * 65]; __shared__ float eq[64 * 65];
  sc_s[wave][lane] = best; id_s[wave][lane] = bidx;
  if (wave == 0) {
#pragma unroll
    for (int c = 0; c < D; ++c) tile[c * 65 + lane] = f[c];
  }
  __syncthreads();
  if (tid < 64) {
    float bs = sc_s[0][tid]; int bi = id_s[0][tid];
#pragma unroll
    for (int wv = 1; wv < 4; ++wv) {
      if (sc_s[wv][tid] < bs) { bs = sc_s[wv][tid]; bi = id_s[wv][tid]; }
    }
    idx_s[tid] = bi;
  }
  __syncthreads();
  float* __restrict__ qout = out;
  float* __restrict__ lat = out + QSZ;
  float* __restrict__ ql = out + 2 * QSZ;
  const size_t n0 = (size_t)bh * 64;
#pragma unroll
  for (int i = 0; i < 16; ++i) {
    const int e_ = i * 256 + tid, w = e_ >> 6, c = e_ & 63;
    const float q = E[idx_s[w] * D + c];
    eq[w * 65 + c] = q;
    ql[(n0 + w) * D + c] = q;
    lat[(n0 + w) * D + c] = tile[c * 65 + w];
  }
  __syncthreads();
  float* __restrict__ qb = qout + (size_t)b * (D * HW) + h * 64;
#pragma unroll
  for (int i = 0; i < 16; ++i) {
    const int e_ = i * 256 + tid, c = e_ >> 6, w = e_ & 63;
    qb[c * HW + w] = eq[w * 65 + c];
  }
}

extern "C" void kernel_launch(void* const* d_in, const int* in_sizes, int n_in,
                              void* d_out, int out_size, void* d_ws, size_t ws_size,
                              hipStream_t stream) {
  const float* X = (const float*)d_in[0];
  const float* E = (const float*)d_in[1];
  float* out = (float*)d_out;
  char* ws = (char*)d_ws;

  if (ws_size >= WS_NEED) {
    float* enorm  = (float*)(ws + WS_ENORM);
    float* enormh = (float*)(ws + WS_ENH);
    unsigned short* Ehi = (unsigned short*)(ws + WS_EHI);
    unsigned short* Elo = (unsigned short*)(ws + WS_ELO);
    int* cnt  = (int*)(ws + WS_CNT);
    int* list = (int*)(ws + WS_LIST);
    prep_kernel<<<KC, 64, 0, stream>>>(E, enorm, enormh, Ehi, Elo, cnt);
    vq_mfma_kernel<<<1024, 256, 0, stream>>>(X, E, enormh, Ehi, Elo, out, cnt, list);
    recheck_kernel<<<512, 64, 0, stream>>>(X, E, enorm, cnt, list, out);
  } else {
    float* enorm = (float*)ws;
    enorm_kernel<<<KC, 64, 0, stream>>>(E, enorm);
    vq_kernel<<<1024, 256, 0, stream>>>(X, E, enorm, out);
  }
}

// Round 7
// 66.784 us; speedup vs baseline: 2.2507x; 1.5149x over previous
//
#include <hip/hip_runtime.h>

static constexpr int  D   = 64;        // embedding dim (C)
static constexpr int  KC  = 1024;      // codebook size
static constexpr int  HW  = 4096;      // 64*64
static constexpr long QSZ = 16L*64*64*64;  // elems per output tensor
static constexpr float GAPT = 0.01f;   // acc-domain gap (= d-gap 0.02); split err ~1e-3

// ---- d_ws layout (bytes) ----
static constexpr size_t WS_ENORM = 0;        // f32[1024]  sum e^2 (recheck)
static constexpr size_t WS_ENH   = 4096;     // f32[1024]  -0.5*sum e^2 (C-init)
static constexpr size_t WS_ES    = 8192;     // u16[131072] staged codebook (256 KB)
                                             //   [chunk32][hi:2048|lo:2048 u16]
                                             //   per table: [g8][col32][8]  (g = dim>>3)
static constexpr size_t WS_CNT   = 270336;   // i32 flagged-row count
static constexpr size_t WS_LIST  = 270340;   // i32[65536] flagged rows
static constexpr size_t WS_NEED  = 532484;

typedef __attribute__((ext_vector_type(8))) short s16x8;   // 8 bf16 (4 VGPR)
typedef __attribute__((ext_vector_type(4))) float f32x4;   // MFMA C/D

__device__ __forceinline__ unsigned short f2bf(float x) {  // RN-even
  union { float f; unsigned u; } v; v.f = x;
  unsigned r = v.u + 0x7FFFu + ((v.u >> 16) & 1u);
  return (unsigned short)(r >> 16);
}
__device__ __forceinline__ float bf2f(unsigned short h) {
  union { unsigned u; float f; } v; v.u = ((unsigned)h) << 16; return v.f;
}
__device__ __forceinline__ void gload_lds16(const void* g, void* l) {
  __builtin_amdgcn_global_load_lds(
      (const __attribute__((address_space(1))) void*)g,
      (__attribute__((address_space(3))) void*)l, 16, 0, 0);
}

// ---------------------------------------------------------------------------
// prep: enorm/enormh[k], bf16 hi/lo split of E into chunked staged layout
// ---------------------------------------------------------------------------
__global__ void __launch_bounds__(64) prep_kernel(const float* __restrict__ E,
                                                  float* __restrict__ enorm,
                                                  float* __restrict__ enormh,
                                                  unsigned short* __restrict__ Es,
                                                  int* __restrict__ cnt) {
  const int k = blockIdx.x, c = threadIdx.x;
  if (k == 0 && c == 0) *cnt = 0;
  const float v = E[k * D + c];
  const unsigned short hb = f2bf(v);
  const unsigned short lb = f2bf(v - bf2f(hb));
  const int chunk = k >> 5, col = k & 31, g = c >> 3, j = c & 7;
  unsigned short* base = Es + (size_t)chunk * 4096 + g * 256 + col * 8 + j;
  base[0]    = hb;
  base[2048] = lb;
  float s = v * v;
#pragma unroll
  for (int off = 32; off; off >>= 1) s += __shfl_down(s, off, 64);
  if (c == 0) { enorm[k] = s; enormh[k] = -0.5f * s; }
}

// ---------------------------------------------------------------------------
// main kernel: 1024 blocks x 256 thr. Block = one (b,h) tile of 64 rows.
// M-split waves: wave owns 16 rows x ALL 1024 cols -> one staged LDS chunk
// serves all 4 waves. 2-phase pipeline: stage chunk t+1 (global_load_lds,
// structural prefetch the reg-allocator can't defeat) while computing chunk
// t from LDS (ds_read_b128 -> 6x MFMA -> 4-op top-2 bookkeeping).
// ---------------------------------------------------------------------------
__global__ void __launch_bounds__(256)
vq_mfma_kernel(const float* __restrict__ X,
               const float* __restrict__ E,
               const float* __restrict__ enormh,
               const unsigned short* __restrict__ Es,
               float* __restrict__ out,
               int* __restrict__ cnt,
               int* __restrict__ list) {
  __shared__ float Xt[64][65];                            // X tile, row-major
  __shared__ float en_s[KC];                              // -0.5*||e||^2
  __shared__ __attribute__((aligned(16))) unsigned short Bs[2][4096];  // 2x8KB chunk
  __shared__ int idx_s[64];

  const int tid  = threadIdx.x;
  const int wave = tid >> 6;
  const int lane = tid & 63;
  const int c15  = lane & 15;
  const int kg   = lane >> 4;
  const int bh   = blockIdx.x;
  const int b    = bh >> 6;
  const int h    = bh & 63;

  // stage chunk 0 immediately (no LDS dependency; latency hides under phase A/B)
  {
    const unsigned short* g0 = Es + wave * 1024 + lane * 8;
#pragma unroll
    for (int is = 0; is < 2; ++is)
      gload_lds16(g0 + is * 512, &Bs[0][wave * 1024 + is * 512]);
  }

  // ---- phase A: stage 64x64 X-slice (transposed) + enormh table ----
  const float* __restrict__ xbase = X + (size_t)b * (D * HW) + h * 64;
  {
    const int w = tid & 63, c0 = tid >> 6;
#pragma unroll
    for (int i = 0; i < 16; ++i)
      Xt[w][c0 + i * 4] = xbase[(c0 + i * 4) * HW + w];  // coalesced; 2-way LDS (free)
#pragma unroll
    for (int i = 0; i < 4; ++i)
      en_s[tid + i * 256] = enormh[tid + i * 256];
  }
  __syncthreads();   // Xt, en_s, Bs[0] all ready (implicit vmcnt drain)

  // ---- phase B: A-fragments (bf16 hi/lo) for this wave's 16 rows ----
  s16x8 ah[2], al[2];
  {
    const int row = wave * 16 + c15;
#pragma unroll
    for (int ks = 0; ks < 2; ++ks) {
      const float* xp = &Xt[row][ks * 32 + kg * 8];
      s16x8 hh, ll;
#pragma unroll
      for (int j = 0; j < 8; ++j) {
        const float x = xp[j];
        const unsigned short hb = f2bf(x);
        hh[j] = (short)hb;
        ll[j] = (short)f2bf(x - bf2f(hb));
      }
      ah[ks] = hh; al[ks] = ll;
    }
  }

  // ---- phase C: sweep 32 chunks of 32 cols, LDS double-buffered ----
  float b1[4], b2[4]; int i1[4];
#pragma unroll
  for (int r = 0; r < 4; ++r) { b1[r] = -3.4e38f; b2[r] = -3.4e38f; i1[r] = 0; }

  for (int t = 0; t < 32; ++t) {
    const int cur = t & 1;
    if (t < 31) {   // stage next chunk into the other buffer
      const unsigned short* g0 = Es + (size_t)(t + 1) * 4096 + wave * 1024 + lane * 8;
#pragma unroll
      for (int is = 0; is < 2; ++is)
        gload_lds16(g0 + is * 512, &Bs[cur ^ 1][wave * 1024 + is * 512]);
    }
#pragma unroll
    for (int ni = 0; ni < 2; ++ni) {
      const int colc = ni * 16 + c15;                 // col within chunk
      const unsigned short* bp = &Bs[cur][colc * 8];  // + g*256, g = ks*4+kg
      const s16x8 h0 = *(const s16x8*)(bp + (kg    ) * 256);
      const s16x8 h1 = *(const s16x8*)(bp + (kg + 4) * 256);
      const s16x8 l0 = *(const s16x8*)(bp + 2048 + (kg    ) * 256);
      const s16x8 l1 = *(const s16x8*)(bp + 2048 + (kg + 4) * 256);
      const int col = t * 32 + colc;
      const float en = en_s[col];
      f32x4 acc = {en, en, en, en};
      acc = __builtin_amdgcn_mfma_f32_16x16x32_bf16(ah[0], h0, acc, 0, 0, 0);
      acc = __builtin_amdgcn_mfma_f32_16x16x32_bf16(al[0], h0, acc, 0, 0, 0);
      acc = __builtin_amdgcn_mfma_f32_16x16x32_bf16(ah[0], l0, acc, 0, 0, 0);
      acc = __builtin_amdgcn_mfma_f32_16x16x32_bf16(ah[1], h1, acc, 0, 0, 0);
      acc = __builtin_amdgcn_mfma_f32_16x16x32_bf16(al[1], h1, acc, 0, 0, 0);
      acc = __builtin_amdgcn_mfma_f32_16x16x32_bf16(ah[1], l1, acc, 0, 0, 0);
#pragma unroll
      for (int r = 0; r < 4; ++r) {
        const float x  = acc[r];
        const bool  gt = x > b1[r];
        b2[r] = __builtin_amdgcn_fmed3f(b2[r], x, b1[r]);  // 2nd-best
        b1[r] = gt ? x   : b1[r];
        i1[r] = gt ? col : i1[r];
      }
    }
    __syncthreads();  // stage t+1 landed; all waves done reading Bs[cur]
  }

  // ---- phase D: merge best/2nd across the 16 col-lanes (MAX semantics) ----
#pragma unroll
  for (int r = 0; r < 4; ++r) {
    float B1 = b1[r], B2 = b2[r]; int I1 = i1[r];
#pragma unroll
    for (int m = 1; m < 16; m <<= 1) {
      const float o1 = __shfl_xor(B1, m, 64);
      const float o2 = __shfl_xor(B2, m, 64);
      const int   oi = __shfl_xor(I1, m, 64);
      const float n2 = fmaxf(fmaxf(B2, o2), fminf(B1, o1));
      if (o1 > B1) { B1 = o1; I1 = oi; }
      B2 = n2;
    }
    if (c15 == 0) {
      const int rl = wave * 16 + kg * 4 + r;   // this wave's row in tile
      idx_s[rl] = I1;
      if (B1 - B2 < GAPT) {                    // near-tie -> exact recheck
        const int pos = atomicAdd(cnt, 1);
        list[pos] = bh * 64 + rl;
      }
    }
  }
  __syncthreads();

  // ---- phase E: outputs (coalesced; eq tile overlaid onto Xt) ----
  float* __restrict__ qout = out;
  float* __restrict__ lat  = out + QSZ;
  float* __restrict__ ql   = out + 2 * QSZ;
  const size_t n0 = (size_t)bh * 64;

#pragma unroll
  for (int i = 0; i < 16; ++i) {
    const int e_ = i * 256 + tid;
    const int w = e_ >> 6, c = e_ & 63;
    const float q = E[idx_s[w] * D + c];    // coalesced gather (w uniform/group)
    ql[(n0 + w) * D + c]  = q;
    lat[(n0 + w) * D + c] = Xt[w][c];
    Xt[w][c] = q;                            // overlay: each slot read then written
  }
  __syncthreads();
  float* __restrict__ qb = qout + (size_t)b * (D * HW) + h * 64;
#pragma unroll
  for (int i = 0; i < 16; ++i) {
    const int e_ = i * 256 + tid;
    const int c = e_ >> 6, w = e_ & 63;
    qb[c * HW + w] = Xt[w][c];
  }
}

// ---------------------------------------------------------------------------
// exact fp32 recheck for flagged rows (lowest-index tie-break), 1 wave/row
// ---------------------------------------------------------------------------
__global__ void __launch_bounds__(64) recheck_kernel(const float* __restrict__ X,
                                                     const float* __restrict__ E,
                                                     const float* __restrict__ enorm,
                                                     const int* __restrict__ cnt,
                                                     const int* __restrict__ list,
                                                     float* __restrict__ out) {
  __shared__ float fsh[64];
  const int lane = threadIdx.x;
  const int n = *cnt;
  for (int ii = blockIdx.x; ii < n; ii += gridDim.x) {
    const int row = list[ii];
    const int b = row >> 12, h = (row >> 6) & 63, w = row & 63;
    fsh[lane] = X[((size_t)b * D + lane) * HW + h * 64 + w];
    __syncthreads();
    float best = 3.4e38f; int bidx = 0;
    for (int j = 0; j < 16; ++j) {
      const int k = lane + j * 64;
      const float* __restrict__ e = E + k * D;
      float a0 = 0.f, a1 = 0.f, a2 = 0.f, a3 = 0.f;
#pragma unroll
      for (int c = 0; c < D; c += 4) {
        a0 = fmaf(fsh[c + 0], e[c + 0], a0);
        a1 = fmaf(fsh[c + 1], e[c + 1], a1);
        a2 = fmaf(fsh[c + 2], e[c + 2], a2);
        a3 = fmaf(fsh[c + 3], e[c + 3], a3);
      }
      const float s = enorm[k] - 2.0f * ((a0 + a1) + (a2 + a3));
      if (s < best) { best = s; bidx = k; }
    }
#pragma unroll
    for (int m = 1; m < 64; m <<= 1) {
      const float ob = __shfl_xor(best, m, 64);
      const int   oi = __shfl_xor(bidx, m, 64);
      if (ob < best || (ob == best && oi < bidx)) { best = ob; bidx = oi; }
    }
    const float q = E[bidx * D + lane];
    float* __restrict__ ql = out + 2 * QSZ;
    ql[(size_t)row * D + lane] = q;
    out[((size_t)b * D + lane) * HW + h * 64 + w] = q;
    __syncthreads();
  }
}

// ---------------------------------------------------------------------------
// fallback (R1 kernels) if ws_size is too small for the staged tables
// ---------------------------------------------------------------------------
__global__ void __launch_bounds__(64) enorm_kernel(const float* __restrict__ E,
                                                   float* __restrict__ enorm) {
  const int k = blockIdx.x, c = threadIdx.x;
  float v = E[k * D + c];
  float s = v * v;
#pragma unroll
  for (int off = 32; off; off >>= 1) s += __shfl_down(s, off, 64);
  if (c == 0) enorm[k] = s;
}

__global__ void __launch_bounds__(256) vq_kernel(const float* __restrict__ X,
                                                 const float* __restrict__ E,
                                                 const float* __restrict__ enorm,
                                                 float* __restrict__ out) {
  const int bh = blockIdx.x, b = bh >> 6, h = bh & 63;
  const int tid = threadIdx.x, wave = tid >> 6, lane = tid & 63;
  const float* __restrict__ xbase = X + (size_t)b * (D * HW) + h * 64;
  float f[D];
#pragma unroll
  for (int c = 0; c < D; ++c) f[c] = xbase[c * HW + lane];
  float best = 3.4e38f; int bidx = 0;
  const int k0 = wave * (KC / 4);
  for (int k = k0; k < k0 + (KC / 4); ++k) {
    const float* __restrict__ e = E + k * D;
    float a0 = 0.f, a1 = 0.f, a2 = 0.f, a3 = 0.f;
#pragma unroll
    for (int c = 0; c < D; c += 4) {
      a0 = fmaf(f[c + 0], e[c + 0], a0);
      a1 = fmaf(f[c + 1], e[c + 1], a1);
      a2 = fmaf(f[c + 2], e[c + 2], a2);
      a3 = fmaf(f[c + 3], e[c + 3], a3);
    }
    const float score = enorm[k] - 2.0f * ((a0 + a1) + (a2 + a3));
    if (score < best) { best = score; bidx = k; }
  }
  __shared__ float sc_s[4][64]; __shared__ int id_s[4][64];
  __shared__ int idx_s[64]; __shared__ float tile[64 * 65]; __shared__ float eq[64 * 65];
  sc_s[wave][lane] = best; id_s[wave][lane] = bidx;
  if (wave == 0) {
#pragma unroll
    for (int c = 0; c < D; ++c) tile[c * 65 + lane] = f[c];
  }
  __syncthreads();
  if (tid < 64) {
    float bs = sc_s[0][tid]; int bi = id_s[0][tid];
#pragma unroll
    for (int wv = 1; wv < 4; ++wv) {
      if (sc_s[wv][tid] < bs) { bs = sc_s[wv][tid]; bi = id_s[wv][tid]; }
    }
    idx_s[tid] = bi;
  }
  __syncthreads();
  float* __restrict__ qout = out;
  float* __restrict__ lat = out + QSZ;
  float* __restrict__ ql = out + 2 * QSZ;
  const size_t n0 = (size_t)bh * 64;
#pragma unroll
  for (int i = 0; i < 16; ++i) {
    const int e_ = i * 256 + tid, w = e_ >> 6, c = e_ & 63;
    const float q = E[idx_s[w] * D + c];
    eq[w * 65 + c] = q;
    ql[(n0 + w) * D + c] = q;
    lat[(n0 + w) * D + c] = tile[c * 65 + w];
  }
  __syncthreads();
  float* __restrict__ qb = qout + (size_t)b * (D * HW) + h * 64;
#pragma unroll
  for (int i = 0; i < 16; ++i) {
    const int e_ = i * 256 + tid, c = e_ >> 6, w = e_ & 63;
    qb[c * HW + w] = eq[w * 65 + c];
  }
}

extern "C" void kernel_launch(void* const* d_in, const int* in_sizes, int n_in,
                              void* d_out, int out_size, void* d_ws, size_t ws_size,
                              hipStream_t stream) {
  const float* X = (const float*)d_in[0];
  const float* E = (const float*)d_in[1];
  float* out = (float*)d_out;
  char* ws = (char*)d_ws;

  if (ws_size >= WS_NEED) {
    float* enorm  = (float*)(ws + WS_ENORM);
    float* enormh = (float*)(ws + WS_ENH);
    unsigned short* Es = (unsigned short*)(ws + WS_ES);
    int* cnt  = (int*)(ws + WS_CNT);
    int* list = (int*)(ws + WS_LIST);
    prep_kernel<<<KC, 64, 0, stream>>>(E, enorm, enormh, Es, cnt);
    vq_mfma_kernel<<<1024, 256, 0, stream>>>(X, E, enormh, Es, out, cnt, list);
    recheck_kernel<<<512, 64, 0, stream>>>(X, E, enorm, cnt, list, out);
  } else {
    float* enorm = (float*)ws;
    enorm_kernel<<<KC, 64, 0, stream>>>(E, enorm);
    vq_kernel<<<1024, 256, 0, stream>>>(X, E, enorm, out);
  }
}